// Round 3
// 63.146 us; speedup vs baseline: 1.0144x; 1.0144x over previous
//
#include <hip/hip_runtime.h>
#include <math.h>

// Inter-prediction: 21x21 search, 4x4 blocks, softmax(-100*meanAbsDiff).
// One wave per 4x4 block; WG=256 (4 waves) = 2x2 block tile.
//
// R6: bisect. R4/R5 (permlane/DPP reductions) both failed correctness with
// O(1) absmax; paper-model says they're right, so some primitive's compiled
// semantics differ from the model. Revert ALL wave reductions to R3's proven
// __shfl_xor code, keep ONLY the staging improvements:
//  - Single-copy col-major window, stride 29 (odd -> mild bank aliasing),
//    read as scalar pairs (compiler merges to ds_read2_b32; no 8B alignment
//    requirement -> R3's parity dual-copy is gone, half the LDS writes).
//  - float2-granular global staging (validity is pairwise: even cols, pad=10
//    even), uniform-branch interior fast path (tr,tc in [2,29]: no checks).
//  - __launch_bounds__(256,4): cap 128 VGPR.

typedef float v2f __attribute__((ext_vector_type(2)));

#define HH 256
#define WW 256
#define PAD 10
#define NR 28
#define NC 28
#define CSTR 29            // odd per-column stride (floats)
#define LDSN (NC * CSTR)   // 812 floats = 3248 B

__global__ __launch_bounds__(256, 4) void pred_kernel(
    const float* __restrict__ im1, const float* __restrict__ im2,
    float* __restrict__ out) {
  __shared__ __attribute__((aligned(16))) float win2[LDSN];

  const int tid = threadIdx.x;
  const int T = blockIdx.x;
  const int b = T >> 10;           // 1024 2x2-block tiles per image
  const int rem = T & 1023;
  const int tr = rem >> 5;
  const int tc = rem & 31;
  const float* im2b = im2 + b * (HH * WW);

  const int wave = tid >> 6;
  const int lane = tid & 63;
  const int by = tr * 2 + (wave >> 1);
  const int bx = tc * 2 + (wave & 1);

  // im1 4x4 block as row-pair v2 per column: a2[col][rp] = {row2rp, row2rp+1}
  v2f a2[4][2];
  {
    const float* im1b = im1 + b * (HH * WW) + (by * 4) * WW + bx * 4;
    const float4 r0 = *reinterpret_cast<const float4*>(im1b + 0 * WW);
    const float4 r1 = *reinterpret_cast<const float4*>(im1b + 1 * WW);
    const float4 r2 = *reinterpret_cast<const float4*>(im1b + 2 * WW);
    const float4 r3 = *reinterpret_cast<const float4*>(im1b + 3 * WW);
    a2[0][0] = (v2f){r0.x, r1.x}; a2[1][0] = (v2f){r0.y, r1.y};
    a2[2][0] = (v2f){r0.z, r1.z}; a2[3][0] = (v2f){r0.w, r1.w};
    a2[0][1] = (v2f){r2.x, r3.x}; a2[1][1] = (v2f){r2.y, r3.y};
    a2[2][1] = (v2f){r2.z, r3.z}; a2[3][1] = (v2f){r2.w, r3.w};
  }

  // Stage 28x28 zero-padded window, col-major stride 29, float2 granularity.
  // gc0 is even -> float2 loads 8B-aligned; a float2's two cols are valid or
  // invalid together (pad width 10 is even).
  {
    const int gr0 = tr * 8 - PAD;
    const int gc0 = tc * 8 - PAD;
    if (((unsigned)(tr - 2) < 28u) & ((unsigned)(tc - 2) < 28u)) {
      // interior: whole window in-bounds, no checks
      for (int e = tid; e < NR * (NC / 2); e += 256) {
        const int r = e / 14;
        const int c2 = e - r * 14;
        const float2 v = *reinterpret_cast<const float2*>(
            &im2b[(gr0 + r) * WW + (gc0 + 2 * c2)]);
        win2[(2 * c2 + 0) * CSTR + r] = v.x;
        win2[(2 * c2 + 1) * CSTR + r] = v.y;
      }
    } else {
      for (int e = tid; e < NR * (NC / 2); e += 256) {
        const int r = e / 14;
        const int c2 = e - r * 14;
        const int gr = gr0 + r;
        const int gc = gc0 + 2 * c2;
        float2 v = {0.f, 0.f};
        if (((unsigned)gr < HH) & ((unsigned)gc < WW))
          v = *reinterpret_cast<const float2*>(&im2b[gr * WW + gc]);
        win2[(2 * c2 + 0) * CSTR + r] = v.x;
        win2[(2 * c2 + 1) * CSTR + r] = v.y;
      }
    }
  }
  __syncthreads();

  // Lane's shift tile: shift row i (dy), shift cols j0..j0+6 (lane 63: dummy).
  const int i = lane / 3;
  const int j0 = (lane - i * 3) * 7;
  const int ir = i + (wave >> 1) * 4;   // window row of shift origin
  const int jc = j0 + (wave & 1) * 4;   // window col of shift origin
  const int baseIdx = (lane == 63) ? 0 : (jc * CSTR + ir);

  // 4x10 register window as row-pair v2s (compiler merges to ds_read2_b32).
  v2f w2[10][2];
#pragma unroll
  for (int c = 0; c < 10; ++c) {
    const float* p = &win2[baseIdx + c * CSTR];
    w2[c][0] = (v2f){p[0], p[1]};
    w2[c][1] = (v2f){p[2], p[3]};
  }

  // Phase 1: 7 SADs (packed).
  float sad[7];
#pragma unroll
  for (int t = 0; t < 7; ++t) {
    v2f acc = (v2f){0.f, 0.f};
#pragma unroll
    for (int c = 0; c < 4; ++c) {
#pragma unroll
      for (int rp = 0; rp < 2; ++rp) {
        const v2f d = a2[c][rp] - w2[t + c][rp];
        acc += __builtin_elementwise_max(d, -d);
      }
    }
    sad[t] = acc.x + acc.y;
  }
  if (lane == 63) {
#pragma unroll
    for (int t = 0; t < 7; ++t) sad[t] = 3.0e38f;
  }

  // Exact global min SAD (= max logit) — R3-proven shuffle butterfly.
  float m = sad[0];
#pragma unroll
  for (int t = 1; t < 7; ++t) m = fminf(m, sad[t]);
#pragma unroll
  for (int off = 32; off; off >>= 1) m = fminf(m, __shfl_xor(m, off, 64));

  // Phase 2: weights + packed FMA accumulation.
  // logit = -6.25*sad; exp2 const cc = 6.25*log2(e).
  const float cc = 9.016844005556021f;
  const float cm = cc * m;
  float l = 0.f;
  v2f o2[4][2];
#pragma unroll
  for (int c = 0; c < 4; ++c)
#pragma unroll
    for (int rp = 0; rp < 2; ++rp) o2[c][rp] = (v2f){0.f, 0.f};
#pragma unroll
  for (int t = 0; t < 7; ++t) {
    const float p = __builtin_amdgcn_exp2f(__builtin_fmaf(-cc, sad[t], cm));
    l += p;
    const v2f pv = (v2f){p, p};
#pragma unroll
    for (int c = 0; c < 4; ++c)
#pragma unroll
      for (int rp = 0; rp < 2; ++rp)
        o2[c][rp] += pv * w2[t + c][rp];   // contracts to v_pk_fma_f32
  }

  // Unpack to o[dy*4+dx] and recursive-halving reduce; lane 4t owns pixel t.
  float o[16];
#pragma unroll
  for (int c = 0; c < 4; ++c)
#pragma unroll
    for (int rp = 0; rp < 2; ++rp) {
      o[(2 * rp + 0) * 4 + c] = o2[c][rp].x;
      o[(2 * rp + 1) * 4 + c] = o2[c][rp].y;
    }

  float r8[8];
  {
    const bool up = (lane & 32) != 0;
#pragma unroll
    for (int q = 0; q < 8; ++q) {
      const float send = up ? o[q] : o[q + 8];
      const float recv = __shfl_xor(send, 32, 64);
      r8[q] = (up ? o[q + 8] : o[q]) + recv;
    }
  }
  float r4[4];
  {
    const bool up = (lane & 16) != 0;
#pragma unroll
    for (int q = 0; q < 4; ++q) {
      const float send = up ? r8[q] : r8[q + 4];
      const float recv = __shfl_xor(send, 16, 64);
      r4[q] = (up ? r8[q + 4] : r8[q]) + recv;
    }
  }
  float r2[2];
  {
    const bool up = (lane & 8) != 0;
#pragma unroll
    for (int q = 0; q < 2; ++q) {
      const float send = up ? r4[q] : r4[q + 2];
      const float recv = __shfl_xor(send, 8, 64);
      r2[q] = (up ? r4[q + 2] : r4[q]) + recv;
    }
  }
  float r1;
  {
    const bool up = (lane & 4) != 0;
    const float send = up ? r2[0] : r2[1];
    const float recv = __shfl_xor(send, 4, 64);
    r1 = (up ? r2[1] : r2[0]) + recv;
  }
  r1 += __shfl_xor(r1, 2, 64);
  r1 += __shfl_xor(r1, 1, 64);

#pragma unroll
  for (int off = 32; off; off >>= 1) l += __shfl_xor(l, off, 64);
  const float rinv = __builtin_amdgcn_rcpf(l);  // l >= 1 always

  if ((lane & 3) == 0) {
    const int t = lane >> 2;       // pixel 0..15
    out[b * (HH * WW) + (by * 4 + (t >> 2)) * WW + bx * 4 + (t & 3)] =
        r1 * rinv;
  }
}

extern "C" void kernel_launch(void* const* d_in, const int* in_sizes, int n_in,
                              void* d_out, int out_size, void* d_ws, size_t ws_size,
                              hipStream_t stream) {
  const float* im1 = (const float*)d_in[0];
  const float* im2 = (const float*)d_in[1];
  float* out = (float*)d_out;
  const int B = in_sizes[0] / (HH * WW);  // 2
  pred_kernel<<<B * 1024, 256, 0, stream>>>(im1, im2, out);
}

// Round 4
// 62.246 us; speedup vs baseline: 1.0291x; 1.0145x over previous
//
#include <hip/hip_runtime.h>
#include <math.h>

// Inter-prediction: 21x21 search, 4x4 blocks, softmax(-100*meanAbsDiff).
// One wave per 4x4 block; WG=256 (4 waves) = 2x2 block tile.
//
// R7 = R6 + DPP exact-xor butterflies for the wave reductions.
//  R4/R5 failed with permlane-swap primitives (asm operand-coalescing, then
//  builtin return-convention); R6 bisect proved staging is innocent. This
//  round uses ONLY three exact-xor DPP patterns via the rocPRIM-standard
//  __builtin_amdgcn_update_dpp:
//    xor1 = quad_perm [1,0,3,2] (0xB1)
//    xor2 = quad_perm [2,3,0,1] (0x4E)
//    xor8 = ROW_ROR:8 within 16-lane row (0x128)
//  in the SAME directional-halving structure as R6's proven shuffles.
//  Offsets 4/16/32 remain proven __shfl_xor. o-reduce stage order reordered
//  to {1,2,8,4,16,32} so the wide stages (14 exchanges) are DPP and only 3
//  swizzles remain; m/l reduces likewise 3 DPP + 3 swizzle.
//  Swizzles/thread: 29 -> 9 (fewer LDS-pipe round-trips + lgkm stalls).
//
//  Ownership after reorder: lane L<16 owns pixel (dy,dx) with
//    dy = 2*(L&1) + ((L>>1)&1),  dx = 2*((L>>3)&1) + ((L>>2)&1).
//
//  Carried from R6: single-copy col-major window stride 29, float2-granular
//  staging w/ interior fast path, __launch_bounds__(256,4).

typedef float v2f __attribute__((ext_vector_type(2)));

#define HH 256
#define WW 256
#define PAD 10
#define NR 28
#define NC 28
#define CSTR 29            // odd per-column stride (floats)
#define LDSN (NC * CSTR)   // 812 floats = 3248 B

// Exact-xor lane exchange on the VALU (no LDS pipe, no lgkmcnt).
// CTRL: 0xB1 = xor1, 0x4E = xor2, 0x128 = xor8 (ROW_ROR:8 on a 16-ring).
template <int CTRL>
__device__ __forceinline__ float dppf(float x) {
  return __builtin_bit_cast(
      float, __builtin_amdgcn_update_dpp(0, __builtin_bit_cast(int, x), CTRL,
                                         0xF, 0xF, true));
}

__global__ __launch_bounds__(256, 4) void pred_kernel(
    const float* __restrict__ im1, const float* __restrict__ im2,
    float* __restrict__ out) {
  __shared__ __attribute__((aligned(16))) float win2[LDSN];

  const int tid = threadIdx.x;
  const int T = blockIdx.x;
  const int b = T >> 10;           // 1024 2x2-block tiles per image
  const int rem = T & 1023;
  const int tr = rem >> 5;
  const int tc = rem & 31;
  const float* im2b = im2 + b * (HH * WW);

  const int wave = tid >> 6;
  const int lane = tid & 63;
  const int by = tr * 2 + (wave >> 1);
  const int bx = tc * 2 + (wave & 1);

  // im1 4x4 block as row-pair v2 per column: a2[col][rp] = {row2rp, row2rp+1}
  v2f a2[4][2];
  {
    const float* im1b = im1 + b * (HH * WW) + (by * 4) * WW + bx * 4;
    const float4 r0 = *reinterpret_cast<const float4*>(im1b + 0 * WW);
    const float4 r1 = *reinterpret_cast<const float4*>(im1b + 1 * WW);
    const float4 r2 = *reinterpret_cast<const float4*>(im1b + 2 * WW);
    const float4 r3 = *reinterpret_cast<const float4*>(im1b + 3 * WW);
    a2[0][0] = (v2f){r0.x, r1.x}; a2[1][0] = (v2f){r0.y, r1.y};
    a2[2][0] = (v2f){r0.z, r1.z}; a2[3][0] = (v2f){r0.w, r1.w};
    a2[0][1] = (v2f){r2.x, r3.x}; a2[1][1] = (v2f){r2.y, r3.y};
    a2[2][1] = (v2f){r2.z, r3.z}; a2[3][1] = (v2f){r2.w, r3.w};
  }

  // Stage 28x28 zero-padded window, col-major stride 29, float2 granularity.
  {
    const int gr0 = tr * 8 - PAD;
    const int gc0 = tc * 8 - PAD;
    if (((unsigned)(tr - 2) < 28u) & ((unsigned)(tc - 2) < 28u)) {
      // interior: whole window in-bounds, no checks
      for (int e = tid; e < NR * (NC / 2); e += 256) {
        const int r = e / 14;
        const int c2 = e - r * 14;
        const float2 v = *reinterpret_cast<const float2*>(
            &im2b[(gr0 + r) * WW + (gc0 + 2 * c2)]);
        win2[(2 * c2 + 0) * CSTR + r] = v.x;
        win2[(2 * c2 + 1) * CSTR + r] = v.y;
      }
    } else {
      for (int e = tid; e < NR * (NC / 2); e += 256) {
        const int r = e / 14;
        const int c2 = e - r * 14;
        const int gr = gr0 + r;
        const int gc = gc0 + 2 * c2;
        float2 v = {0.f, 0.f};
        if (((unsigned)gr < HH) & ((unsigned)gc < WW))
          v = *reinterpret_cast<const float2*>(&im2b[gr * WW + gc]);
        win2[(2 * c2 + 0) * CSTR + r] = v.x;
        win2[(2 * c2 + 1) * CSTR + r] = v.y;
      }
    }
  }
  __syncthreads();

  // Lane's shift tile: shift row i (dy), shift cols j0..j0+6 (lane 63: dummy).
  const int i = lane / 3;
  const int j0 = (lane - i * 3) * 7;
  const int ir = i + (wave >> 1) * 4;   // window row of shift origin
  const int jc = j0 + (wave & 1) * 4;   // window col of shift origin
  const int baseIdx = (lane == 63) ? 0 : (jc * CSTR + ir);

  // 4x10 register window as row-pair v2s (compiler merges to ds_read2_b32).
  v2f w2[10][2];
#pragma unroll
  for (int c = 0; c < 10; ++c) {
    const float* p = &win2[baseIdx + c * CSTR];
    w2[c][0] = (v2f){p[0], p[1]};
    w2[c][1] = (v2f){p[2], p[3]};
  }

  // Phase 1: 7 SADs (packed).
  float sad[7];
#pragma unroll
  for (int t = 0; t < 7; ++t) {
    v2f acc = (v2f){0.f, 0.f};
#pragma unroll
    for (int c = 0; c < 4; ++c) {
#pragma unroll
      for (int rp = 0; rp < 2; ++rp) {
        const v2f d = a2[c][rp] - w2[t + c][rp];
        acc += __builtin_elementwise_max(d, -d);
      }
    }
    sad[t] = acc.x + acc.y;
  }
  if (lane == 63) {
#pragma unroll
    for (int t = 0; t < 7; ++t) sad[t] = 3.0e38f;
  }

  // Exact global min SAD (= max logit): lane-local tree, then xor-butterfly
  // {1,2 via DPP, 4 via shfl, 8 via DPP, 16,32 via shfl}.
  float m;
  {
    const float m0 = fminf(sad[0], sad[1]);
    const float m1 = fminf(sad[2], sad[3]);
    const float m2 = fminf(sad[4], sad[5]);
    m = fminf(fminf(m0, m1), fminf(m2, sad[6]));
  }
  m = fminf(m, dppf<0xB1>(m));          // xor1
  m = fminf(m, dppf<0x4E>(m));          // xor2
  m = fminf(m, __shfl_xor(m, 4, 64));   // xor4
  m = fminf(m, dppf<0x128>(m));         // xor8
  m = fminf(m, __shfl_xor(m, 16, 64));  // xor16
  m = fminf(m, __shfl_xor(m, 32, 64));  // xor32

  // Phase 2: weights + packed FMA accumulation.
  // logit = -6.25*sad; exp2 const cc = 6.25*log2(e).
  const float cc = 9.016844005556021f;
  const float cm = cc * m;
  float l = 0.f;
  v2f o2[4][2];
#pragma unroll
  for (int c = 0; c < 4; ++c)
#pragma unroll
    for (int rp = 0; rp < 2; ++rp) o2[c][rp] = (v2f){0.f, 0.f};
#pragma unroll
  for (int t = 0; t < 7; ++t) {
    const float p = __builtin_amdgcn_exp2f(__builtin_fmaf(-cc, sad[t], cm));
    l += p;
    const v2f pv = (v2f){p, p};
#pragma unroll
    for (int c = 0; c < 4; ++c)
#pragma unroll
      for (int rp = 0; rp < 2; ++rp)
        o2[c][rp] += pv * w2[t + c][rp];   // contracts to v_pk_fma_f32
  }

  // Unpack to o[dy*4+dx]. Recursive halving in stage order {1,2,8,4}, then
  // butterflies {16,32}. Wide stages on DPP, narrow on proven shfl.
  float o[16];
#pragma unroll
  for (int c = 0; c < 4; ++c)
#pragma unroll
    for (int rp = 0; rp < 2; ++rp) {
      o[(2 * rp + 0) * 4 + c] = o2[c][rp].x;
      o[(2 * rp + 1) * 4 + c] = o2[c][rp].y;
    }

  float r8[8];
  {
    const bool t1 = (lane & 1) != 0;     // d=1 (quad_perm xor1)
#pragma unroll
    for (int q = 0; q < 8; ++q) {
      const float send = t1 ? o[q] : o[q + 8];
      const float recv = dppf<0xB1>(send);
      r8[q] = (t1 ? o[q + 8] : o[q]) + recv;
    }
  }
  float r4[4];
  {
    const bool t2 = (lane & 2) != 0;     // d=2 (quad_perm xor2)
#pragma unroll
    for (int q = 0; q < 4; ++q) {
      const float send = t2 ? r8[q] : r8[q + 4];
      const float recv = dppf<0x4E>(send);
      r4[q] = (t2 ? r8[q + 4] : r8[q]) + recv;
    }
  }
  float r2[2];
  {
    const bool t8 = (lane & 8) != 0;     // d=8 (ror8 == xor8 in 16-ring)
#pragma unroll
    for (int q = 0; q < 2; ++q) {
      const float send = t8 ? r4[q] : r4[q + 2];
      const float recv = dppf<0x128>(send);
      r2[q] = (t8 ? r4[q + 2] : r4[q]) + recv;
    }
  }
  float r1;
  {
    const bool t4 = (lane & 4) != 0;     // d=4 (shfl)
    const float send = t4 ? r2[0] : r2[1];
    const float recv = __shfl_xor(send, 4, 64);
    r1 = (t4 ? r2[1] : r2[0]) + recv;
  }
  r1 += __shfl_xor(r1, 16, 64);
  r1 += __shfl_xor(r1, 32, 64);

  // l-reduce: same xor-butterfly mix.
  l += dppf<0xB1>(l);
  l += dppf<0x4E>(l);
  l += __shfl_xor(l, 4, 64);
  l += dppf<0x128>(l);
  l += __shfl_xor(l, 16, 64);
  l += __shfl_xor(l, 32, 64);
  const float rinv = __builtin_amdgcn_rcpf(l);  // l >= 1 always

  // Ownership from stage order: q bit3=lane0, bit2=lane1, bit1=lane3,
  // bit0=lane2  ->  dy = 2*L0 + L1, dx = 2*L3 + L2. Lanes 0..15 write.
  if (lane < 16) {
    const int dy = ((lane & 1) << 1) | ((lane >> 1) & 1);
    const int dx = ((lane & 8) >> 2) | ((lane & 4) >> 2);
    out[b * (HH * WW) + (by * 4 + dy) * WW + bx * 4 + dx] = r1 * rinv;
  }
}

extern "C" void kernel_launch(void* const* d_in, const int* in_sizes, int n_in,
                              void* d_out, int out_size, void* d_ws, size_t ws_size,
                              hipStream_t stream) {
  const float* im1 = (const float*)d_in[0];
  const float* im2 = (const float*)d_in[1];
  float* out = (float*)d_out;
  const int B = in_sizes[0] / (HH * WW);  // 2
  pred_kernel<<<B * 1024, 256, 0, stream>>>(im1, im2, out);
}